// Round 1
// baseline (1253.103 us; speedup 1.0000x reference)
//
#include <hip/hip_runtime.h>
#include <math.h>

#define IMH 480
#define IMW 640
#define HW (IMH*IMW)
#define KPT 512
#define DESC 256
#define CAP 131072
#define NMSR 3

// ---------------------------------------------------------------- MT19937
// Replicates np.random.RandomState(42).uniform(-8,8,(256,4)) -> round -> int
__global__ void init_offsets_kernel(int* __restrict__ offs) {
  __shared__ unsigned int mt[624];
  if (threadIdx.x != 0 || blockIdx.x != 0) return;
  unsigned int s = 42u;
  for (int i = 0; i < 624; ++i) { mt[i] = s; s = 1812433253u * (s ^ (s >> 30)) + (unsigned)i + 1u; }
  int mti = 624;
  for (int i = 0; i < 1024; ++i) {
    unsigned int draw[2];
    for (int d = 0; d < 2; ++d) {
      if (mti >= 624) {
        for (int kk = 0; kk < 624; ++kk) {
          unsigned int y = (mt[kk] & 0x80000000u) | (mt[(kk + 1) % 624] & 0x7fffffffu);
          unsigned int v = mt[(kk + 397) % 624] ^ (y >> 1);
          if (y & 1u) v ^= 0x9908b0dfu;
          mt[kk] = v;
        }
        mti = 0;
      }
      unsigned int y = mt[mti++];
      y ^= (y >> 11);
      y ^= (y << 7)  & 0x9d2c5680u;
      y ^= (y << 15) & 0xefc60000u;
      y ^= (y >> 18);
      draw[d] = y;
    }
    double r = ((double)(draw[0] >> 5) * 67108864.0 + (double)(draw[1] >> 6)) / 9007199254740992.0;
    double val = -8.0 + 16.0 * r;
    offs[i] = (int)rint(val);   // round half to even, like np.round
  }
}

__global__ void init_misc_kernel(int* __restrict__ counts, float* __restrict__ sel_val,
                                 int* __restrict__ sel_idx, float* __restrict__ u,
                                 float* __restrict__ v) {
  int t = blockIdx.x * blockDim.x + threadIdx.x;
  if (t < 2) counts[t] = 0;
  if (t < 2 * KPT) { sel_val[t] = 0.f; sel_idx[t] = -1; }
  if (t < KPT + 1) { u[t] = 0.f; v[t] = 0.f; }
}

// ---------------------------------------------------------------- detector
__global__ void detector_kernel(const float* __restrict__ img0, const float* __restrict__ img1,
                                float* __restrict__ scores, float* __restrict__ smooth) {
  int t = blockIdx.x * blockDim.x + threadIdx.x;
  if (t >= 2 * HW) return;
  int b = t / HW;
  int p = t - b * HW;
  int y = p / IMW;
  int x = p - y * IMW;
  const float* __restrict__ img = b ? img1 : img0;
  float a[5][5];
  #pragma unroll
  for (int i = 0; i < 5; ++i) {
    int yy = y + i - 2;
    #pragma unroll
    for (int j = 0; j < 5; ++j) {
      int xx = x + j - 2;
      a[i][j] = (yy >= 0 && yy < IMH && xx >= 0 && xx < IMW) ? img[yy * IMW + xx] : 0.f;
    }
  }
  float sm = 0.f;
  #pragma unroll
  for (int i = 0; i < 5; ++i)
    #pragma unroll
    for (int j = 0; j < 5; ++j) sm += a[i][j];
  smooth[t] = sm * (1.f / 25.f);

  float sxx = 0.f, syy = 0.f, sxy = 0.f;
  #pragma unroll
  for (int cy = -1; cy <= 1; ++cy) {
    #pragma unroll
    for (int cx = -1; cx <= 1; ++cx) {
      int yy = y + cy, xx = x + cx;
      if (yy < 0 || yy >= IMH || xx < 0 || xx >= IMW) continue;  // zero-pad box conv
      int iu = cy + 2, iv = cx + 2;
      float ix = (a[iu - 1][iv + 1] - a[iu - 1][iv - 1])
               + 2.f * (a[iu][iv + 1] - a[iu][iv - 1])
               + (a[iu + 1][iv + 1] - a[iu + 1][iv - 1]);
      float iy = (a[iu + 1][iv - 1] + 2.f * a[iu + 1][iv] + a[iu + 1][iv + 1])
               - (a[iu - 1][iv - 1] + 2.f * a[iu - 1][iv] + a[iu - 1][iv + 1]);
      sxx += ix * ix; syy += iy * iy; sxy += ix * iy;
    }
  }
  sxx *= (1.f / 9.f); syy *= (1.f / 9.f); sxy *= (1.f / 9.f);
  float half_tr = 0.5f * (sxx + syy);
  float hd = 0.5f * (sxx - syy);
  scores[t] = half_tr - sqrtf(hd * hd + sxy * sxy + 1e-12f);
}

// ---------------------------------------------------------------- NMS + compact
__global__ void nms_cand_kernel(const float* __restrict__ scores,
                                float* __restrict__ cand_val, int* __restrict__ cand_idx,
                                int* __restrict__ counts) {
  int t = blockIdx.x * blockDim.x + threadIdx.x;
  if (t >= 2 * HW) return;
  int b = t / HW;
  int p = t - b * HW;
  int y = p / IMW;
  int x = p - y * IMW;
  const float* sc = scores + b * HW;
  float s = sc[p];
  if (s <= 0.f) return;   // s*mask must be > 0 anyway
  float m = -INFINITY;
  int y0 = max(y - NMSR, 0), y1 = min(y + NMSR, IMH - 1);
  int x0 = max(x - NMSR, 0), x1 = min(x + NMSR, IMW - 1);
  for (int yy = y0; yy <= y1; ++yy)
    for (int xx = x0; xx <= x1; ++xx)
      m = fmaxf(m, sc[yy * IMW + xx]);
  if (s >= m - 1e-7f) {
    int slot = atomicAdd(&counts[b], 1);
    if (slot < CAP) {
      cand_val[b * CAP + slot] = s;
      cand_idx[b * CAP + slot] = p;
    }
  }
}

// ---------------------------------------------------------------- exact top-512 (stable order)
__global__ void select_topk_kernel(const float* __restrict__ cand_val, const int* __restrict__ cand_idx,
                                   const int* __restrict__ counts,
                                   float* __restrict__ sel_val, int* __restrict__ sel_idx) {
  int b = blockIdx.y;
  int i = blockIdx.x * blockDim.x + threadIdx.x;
  int n = counts[b]; if (n > CAP) n = CAP;
  if (i >= n) return;
  const float* cv = cand_val + b * CAP;
  const int* ci = cand_idx + b * CAP;
  float vi = cv[i]; int ii = ci[i];
  int rank = 0;
  for (int j = 0; j < n; ++j) {
    float vj = cv[j]; int ij = ci[j];
    rank += ((vj > vi) || (vj == vi && ij < ii)) ? 1 : 0;
  }
  if (rank < KPT) {
    sel_val[b * KPT + rank] = vi;
    sel_idx[b * KPT + rank] = ii;
  }
}

// ---------------------------------------------------------------- kp out + BAD desc + L2 norm
__global__ void kp_desc_kernel(const float* __restrict__ sel_val, const int* __restrict__ sel_idx,
                               const float* __restrict__ smooth, const int* __restrict__ offs,
                               float* __restrict__ desc, float* __restrict__ a2_out,
                               float* __restrict__ out) {
  int blk = blockIdx.x;          // 0..1023
  int b = blk >> 9;
  int k = blk & 511;
  int lane = threadIdx.x;        // 0..63 (one wave)
  float val = sel_val[b * KPT + k];
  int idx = sel_idx[b * KPT + k];
  bool valid = (val > 0.f) && (idx >= 0);
  int y = 0, x = 0;
  if (valid) { y = idx / IMW; x = idx - y * IMW; }
  const float* sm = smooth + b * HW;
  float d[4];
  #pragma unroll
  for (int t2 = 0; t2 < 4; ++t2) {
    int pp = (lane << 2) + t2;
    int oy1 = offs[4 * pp + 0], ox1 = offs[4 * pp + 1];
    int oy2 = offs[4 * pp + 2], ox2 = offs[4 * pp + 3];
    int ya = min(max(y + oy1, 0), IMH - 1), xa = min(max(x + ox1, 0), IMW - 1);
    int yb = min(max(y + oy2, 0), IMH - 1), xb = min(max(x + ox2, 0), IMW - 1);
    float v2 = sm[ya * IMW + xa] - sm[yb * IMW + xb];
    d[t2] = valid ? v2 : 0.f;
  }
  float ss = d[0] * d[0] + d[1] * d[1] + d[2] * d[2] + d[3] * d[3];
  #pragma unroll
  for (int off = 32; off; off >>= 1) ss += __shfl_down(ss, off);
  ss = __shfl(ss, 0);
  float scale = 1.f / (sqrtf(ss) + 1e-8f);
  float* dd = desc + (size_t)(b * KPT + k) * DESC;
  #pragma unroll
  for (int t2 = 0; t2 < 4; ++t2) dd[(lane << 2) + t2] = d[t2] * scale;
  if (lane == 0) {
    a2_out[b * KPT + k] = ss * scale * scale;
    float* kp = out + b * (2 * KPT) + k * 2;
    kp[0] = valid ? (float)y : -1.f;
    kp[1] = valid ? (float)x : -1.f;
  }
}

// ---------------------------------------------------------------- Z = sim with dustbin
__global__ void similarity_kernel(const float* __restrict__ desc, const float* __restrict__ a2,
                                  float* __restrict__ Z) {
  int t = blockIdx.x * blockDim.x + threadIdx.x;
  if (t >= 513 * 513) return;
  int k = t / 513;
  int l = t - k * 513;
  float z;
  if (k == KPT || l == KPT) {
    z = 1.0f;   // UNUSED / EPSILON
  } else {
    const float* d1 = desc + (size_t)k * DESC;
    const float* d2 = desc + (size_t)(KPT + l) * DESC;
    float dot = 0.f;
    #pragma unroll 8
    for (int d = 0; d < DESC; ++d) dot += d1[d] * d2[d];
    float sq = a2[k] + a2[KPT + l] - 2.f * dot;
    sq = fmaxf(sq, 0.f);
    z = -sqrtf(sq + 1e-12f);
  }
  Z[t] = z;
}

// ---------------------------------------------------------------- sinkhorn halves
__device__ __forceinline__ float blk_reduce_max(float val, float* red) {
  #pragma unroll
  for (int off = 32; off; off >>= 1) val = fmaxf(val, __shfl_down(val, off));
  if ((threadIdx.x & 63) == 0) red[threadIdx.x >> 6] = val;
  __syncthreads();
  float r = fmaxf(fmaxf(red[0], red[1]), fmaxf(red[2], red[3]));
  __syncthreads();
  return r;
}

__device__ __forceinline__ float blk_reduce_sum(float val, float* red) {
  #pragma unroll
  for (int off = 32; off; off >>= 1) val += __shfl_down(val, off);
  if ((threadIdx.x & 63) == 0) red[threadIdx.x >> 6] = val;
  __syncthreads();
  float r = (red[0] + red[1]) + (red[2] + red[3]);
  __syncthreads();
  return r;
}

__global__ void sinkhorn_u_kernel(const float* __restrict__ Z, const float* __restrict__ v,
                                  float* __restrict__ u) {
  int k = blockIdx.x;           // 0..512
  __shared__ float red[4];
  const float* row = Z + (size_t)k * 513;
  int tid = threadIdx.x;
  float lm = -INFINITY;
  for (int l = tid; l < 513; l += 256) lm = fmaxf(lm, row[l] + v[l]);
  float m = blk_reduce_max(lm, red);
  float lsum = 0.f;
  for (int l = tid; l < 513; l += 256) lsum += expf(row[l] + v[l] - m);
  float s = blk_reduce_sum(lsum, red);
  if (tid == 0) {
    const float norm = -logf(1024.0f);
    float lmu = (k == KPT) ? (logf(512.0f) + norm) : norm;
    u[k] = lmu - (logf(s) + m);
  }
}

__global__ void sinkhorn_v_kernel(const float* __restrict__ Z, const float* __restrict__ u,
                                  float* __restrict__ v) {
  int l = blockIdx.x;           // 0..512
  __shared__ float red[4];
  int tid = threadIdx.x;
  float lm = -INFINITY;
  for (int kk = tid; kk < 513; kk += 256) lm = fmaxf(lm, Z[(size_t)kk * 513 + l] + u[kk]);
  float m = blk_reduce_max(lm, red);
  float lsum = 0.f;
  for (int kk = tid; kk < 513; kk += 256) lsum += expf(Z[(size_t)kk * 513 + l] + u[kk] - m);
  float s = blk_reduce_sum(lsum, red);
  if (tid == 0) {
    const float norm = -logf(1024.0f);
    float lnu = (l == KPT) ? (logf(512.0f) + norm) : norm;
    v[l] = lnu - (logf(s) + m);
  }
}

__global__ void probs_kernel(const float* __restrict__ Z, const float* __restrict__ u,
                             const float* __restrict__ v, float* __restrict__ out) {
  int t = blockIdx.x * blockDim.x + threadIdx.x;
  if (t >= 513 * 513) return;
  int k = t / 513;
  int l = t - k * 513;
  const float norm = -logf(1024.0f);
  float arg = Z[t] + u[k];
  arg += v[l];
  arg -= norm;
  out[t] = expf(arg);
}

// ---------------------------------------------------------------- launch
extern "C" void kernel_launch(void* const* d_in, const int* in_sizes, int n_in,
                              void* d_out, int out_size, void* d_ws, size_t ws_size,
                              hipStream_t stream) {
  const float* img1 = (const float*)d_in[0];
  const float* img2 = (const float*)d_in[1];
  float* out = (float*)d_out;

  char* p = (char*)d_ws;
  auto alloc = [&](size_t bytes) { char* r = p; p += (bytes + 255) & ~(size_t)255; return r; };
  int*   offs     = (int*)alloc(1024 * 4);
  int*   counts   = (int*)alloc(2 * 4);
  float* sel_val  = (float*)alloc(2 * KPT * 4);
  int*   sel_idx  = (int*)alloc(2 * KPT * 4);
  float* uu       = (float*)alloc(513 * 4);
  float* vv       = (float*)alloc(513 * 4);
  float* a2       = (float*)alloc(2 * KPT * 4);
  float* scores   = (float*)alloc((size_t)2 * HW * 4);
  float* smooth   = (float*)alloc((size_t)2 * HW * 4);
  float* cand_val = (float*)alloc((size_t)2 * CAP * 4);
  int*   cand_idx = (int*)alloc((size_t)2 * CAP * 4);
  float* desc     = (float*)alloc((size_t)2 * KPT * DESC * 4);
  float* Z        = (float*)alloc((size_t)513 * 513 * 4);

  init_offsets_kernel<<<1, 64, 0, stream>>>(offs);
  init_misc_kernel<<<8, 256, 0, stream>>>(counts, sel_val, sel_idx, uu, vv);
  detector_kernel<<<(2 * HW + 255) / 256, 256, 0, stream>>>(img1, img2, scores, smooth);
  nms_cand_kernel<<<(2 * HW + 255) / 256, 256, 0, stream>>>(scores, cand_val, cand_idx, counts);
  select_topk_kernel<<<dim3(CAP / 256, 2), 256, 0, stream>>>(cand_val, cand_idx, counts, sel_val, sel_idx);
  kp_desc_kernel<<<1024, 64, 0, stream>>>(sel_val, sel_idx, smooth, offs, desc, a2, out);
  similarity_kernel<<<(513 * 513 + 255) / 256, 256, 0, stream>>>(desc, a2, Z);
  for (int it = 0; it < 20; ++it) {
    sinkhorn_u_kernel<<<513, 256, 0, stream>>>(Z, vv, uu);
    sinkhorn_v_kernel<<<513, 256, 0, stream>>>(Z, uu, vv);
  }
  probs_kernel<<<(513 * 513 + 255) / 256, 256, 0, stream>>>(Z, uu, vv, out + 2048);
}

// Round 2
// 833.270 us; speedup vs baseline: 1.5038x; 1.5038x over previous
//
#include <hip/hip_runtime.h>
#include <math.h>

#define IMH 480
#define IMW 640
#define HW (IMH*IMW)
#define KPT 512
#define DESC 256
#define CAP 32768
#define NMSR 3

// ---------------------------------------------------------------- MT19937
// Replicates np.random.RandomState(42).uniform(-8,8,(256,4)) -> round -> int
__global__ void init_offsets_kernel(int* __restrict__ offs) {
  __shared__ unsigned int mt[624];
  if (threadIdx.x != 0 || blockIdx.x != 0) return;
  unsigned int s = 42u;
  for (int i = 0; i < 624; ++i) { mt[i] = s; s = 1812433253u * (s ^ (s >> 30)) + (unsigned)i + 1u; }
  int mti = 624;
  for (int i = 0; i < 1024; ++i) {
    unsigned int draw[2];
    for (int d = 0; d < 2; ++d) {
      if (mti >= 624) {
        for (int kk = 0; kk < 624; ++kk) {
          unsigned int y = (mt[kk] & 0x80000000u) | (mt[(kk + 1) % 624] & 0x7fffffffu);
          unsigned int v = mt[(kk + 397) % 624] ^ (y >> 1);
          if (y & 1u) v ^= 0x9908b0dfu;
          mt[kk] = v;
        }
        mti = 0;
      }
      unsigned int y = mt[mti++];
      y ^= (y >> 11);
      y ^= (y << 7)  & 0x9d2c5680u;
      y ^= (y << 15) & 0xefc60000u;
      y ^= (y >> 18);
      draw[d] = y;
    }
    double r = ((double)(draw[0] >> 5) * 67108864.0 + (double)(draw[1] >> 6)) / 9007199254740992.0;
    double val = -8.0 + 16.0 * r;
    offs[i] = (int)rint(val);   // round half to even, like np.round
  }
}

__global__ void init_misc_kernel(int* __restrict__ counts, float* __restrict__ sel_val,
                                 int* __restrict__ sel_idx, float* __restrict__ u,
                                 float* __restrict__ v) {
  int t = blockIdx.x * blockDim.x + threadIdx.x;
  if (t < 2) counts[t] = 0;
  if (t < 2 * KPT) { sel_val[t] = 0.f; sel_idx[t] = -1; }
  if (t < KPT + 1) { u[t] = 0.f; v[t] = 0.f; }
}

// ---------------------------------------------------------------- detector
__global__ void detector_kernel(const float* __restrict__ img0, const float* __restrict__ img1,
                                float* __restrict__ scores, float* __restrict__ smooth) {
  int t = blockIdx.x * blockDim.x + threadIdx.x;
  if (t >= 2 * HW) return;
  int b = t / HW;
  int p = t - b * HW;
  int y = p / IMW;
  int x = p - y * IMW;
  const float* __restrict__ img = b ? img1 : img0;
  float a[5][5];
  #pragma unroll
  for (int i = 0; i < 5; ++i) {
    int yy = y + i - 2;
    #pragma unroll
    for (int j = 0; j < 5; ++j) {
      int xx = x + j - 2;
      a[i][j] = (yy >= 0 && yy < IMH && xx >= 0 && xx < IMW) ? img[yy * IMW + xx] : 0.f;
    }
  }
  float sm = 0.f;
  #pragma unroll
  for (int i = 0; i < 5; ++i)
    #pragma unroll
    for (int j = 0; j < 5; ++j) sm += a[i][j];
  smooth[t] = sm * (1.f / 25.f);

  float sxx = 0.f, syy = 0.f, sxy = 0.f;
  #pragma unroll
  for (int cy = -1; cy <= 1; ++cy) {
    #pragma unroll
    for (int cx = -1; cx <= 1; ++cx) {
      int yy = y + cy, xx = x + cx;
      if (yy < 0 || yy >= IMH || xx < 0 || xx >= IMW) continue;  // zero-pad box conv
      int iu = cy + 2, iv = cx + 2;
      float ix = (a[iu - 1][iv + 1] - a[iu - 1][iv - 1])
               + 2.f * (a[iu][iv + 1] - a[iu][iv - 1])
               + (a[iu + 1][iv + 1] - a[iu + 1][iv - 1]);
      float iy = (a[iu + 1][iv - 1] + 2.f * a[iu + 1][iv] + a[iu + 1][iv + 1])
               - (a[iu - 1][iv - 1] + 2.f * a[iu - 1][iv] + a[iu - 1][iv + 1]);
      sxx += ix * ix; syy += iy * iy; sxy += ix * iy;
    }
  }
  sxx *= (1.f / 9.f); syy *= (1.f / 9.f); sxy *= (1.f / 9.f);
  float half_tr = 0.5f * (sxx + syy);
  float hd = 0.5f * (sxx - syy);
  scores[t] = half_tr - sqrtf(hd * hd + sxy * sxy + 1e-12f);
}

// ---------------------------------------------------------------- NMS + compact
__global__ void nms_cand_kernel(const float* __restrict__ scores,
                                float* __restrict__ cand_val, int* __restrict__ cand_idx,
                                int* __restrict__ counts) {
  int t = blockIdx.x * blockDim.x + threadIdx.x;
  if (t >= 2 * HW) return;
  int b = t / HW;
  int p = t - b * HW;
  int y = p / IMW;
  int x = p - y * IMW;
  const float* sc = scores + b * HW;
  float s = sc[p];
  if (s <= 0.f) return;   // s*mask must be > 0 anyway
  float m = -INFINITY;
  int y0 = max(y - NMSR, 0), y1 = min(y + NMSR, IMH - 1);
  int x0 = max(x - NMSR, 0), x1 = min(x + NMSR, IMW - 1);
  for (int yy = y0; yy <= y1; ++yy)
    for (int xx = x0; xx <= x1; ++xx)
      m = fmaxf(m, sc[yy * IMW + xx]);
  if (s >= m - 1e-7f) {
    int slot = atomicAdd(&counts[b], 1);
    if (slot < CAP) {
      cand_val[b * CAP + slot] = s;
      cand_idx[b * CAP + slot] = p;
    }
  }
}

// ---------------------------------------------------------------- exact top-512 (stable order)
// LDS-tiled O(n^2) rank selection: block caches 256-candidate tiles; all
// threads compare against the tile via LDS broadcast reads (conflict-free).
__global__ void select_topk_kernel(const float* __restrict__ cand_val, const int* __restrict__ cand_idx,
                                   const int* __restrict__ counts,
                                   float* __restrict__ sel_val, int* __restrict__ sel_idx) {
  int b = blockIdx.y;
  int n = counts[b]; if (n > CAP) n = CAP;
  if ((int)(blockIdx.x * 256) >= n) return;   // block-uniform early exit
  int i = blockIdx.x * 256 + threadIdx.x;
  const float* cv = cand_val + b * CAP;
  const int* ci = cand_idx + b * CAP;
  bool active = (i < n);
  float vi = active ? cv[i] : 0.f;
  int ii = active ? ci[i] : 0x7fffffff;
  __shared__ float sv[256];
  __shared__ int si[256];
  int rank = 0;
  for (int base = 0; base < n; base += 256) {
    int j = base + (int)threadIdx.x;
    sv[threadIdx.x] = (j < n) ? cv[j] : -INFINITY;   // sentinel never outranks (vi > 0)
    si[threadIdx.x] = (j < n) ? ci[j] : 0x7fffffff;
    __syncthreads();
    #pragma unroll 8
    for (int t = 0; t < 256; ++t) {
      float vj = sv[t]; int ij = si[t];
      rank += ((vj > vi) || (vj == vi && ij < ii)) ? 1 : 0;
    }
    __syncthreads();
  }
  if (active && rank < KPT) {
    sel_val[b * KPT + rank] = vi;
    sel_idx[b * KPT + rank] = ii;
  }
}

// ---------------------------------------------------------------- kp out + BAD desc + L2 norm
__global__ void kp_desc_kernel(const float* __restrict__ sel_val, const int* __restrict__ sel_idx,
                               const float* __restrict__ smooth, const int* __restrict__ offs,
                               float* __restrict__ desc, float* __restrict__ a2_out,
                               float* __restrict__ out) {
  int blk = blockIdx.x;          // 0..1023
  int b = blk >> 9;
  int k = blk & 511;
  int lane = threadIdx.x;        // 0..63 (one wave)
  float val = sel_val[b * KPT + k];
  int idx = sel_idx[b * KPT + k];
  bool valid = (val > 0.f) && (idx >= 0);
  int y = 0, x = 0;
  if (valid) { y = idx / IMW; x = idx - y * IMW; }
  const float* sm = smooth + b * HW;
  float d[4];
  #pragma unroll
  for (int t2 = 0; t2 < 4; ++t2) {
    int pp = (lane << 2) + t2;
    int oy1 = offs[4 * pp + 0], ox1 = offs[4 * pp + 1];
    int oy2 = offs[4 * pp + 2], ox2 = offs[4 * pp + 3];
    int ya = min(max(y + oy1, 0), IMH - 1), xa = min(max(x + ox1, 0), IMW - 1);
    int yb = min(max(y + oy2, 0), IMH - 1), xb = min(max(x + ox2, 0), IMW - 1);
    float v2 = sm[ya * IMW + xa] - sm[yb * IMW + xb];
    d[t2] = valid ? v2 : 0.f;
  }
  float ss = d[0] * d[0] + d[1] * d[1] + d[2] * d[2] + d[3] * d[3];
  #pragma unroll
  for (int off = 32; off; off >>= 1) ss += __shfl_down(ss, off);
  ss = __shfl(ss, 0);
  float scale = 1.f / (sqrtf(ss) + 1e-8f);
  float* dd = desc + (size_t)(b * KPT + k) * DESC;
  #pragma unroll
  for (int t2 = 0; t2 < 4; ++t2) dd[(lane << 2) + t2] = d[t2] * scale;
  if (lane == 0) {
    a2_out[b * KPT + k] = ss * scale * scale;
    float* kp = out + b * (2 * KPT) + k * 2;
    kp[0] = valid ? (float)y : -1.f;
    kp[1] = valid ? (float)x : -1.f;
  }
}

// ---------------------------------------------------------------- Z = sim with dustbin
__global__ void similarity_kernel(const float* __restrict__ desc, const float* __restrict__ a2,
                                  float* __restrict__ Z) {
  int t = blockIdx.x * blockDim.x + threadIdx.x;
  if (t >= 513 * 513) return;
  int k = t / 513;
  int l = t - k * 513;
  float z;
  if (k == KPT || l == KPT) {
    z = 1.0f;   // UNUSED / EPSILON
  } else {
    const float* d1 = desc + (size_t)k * DESC;
    const float* d2 = desc + (size_t)(KPT + l) * DESC;
    float dot = 0.f;
    #pragma unroll 8
    for (int d = 0; d < DESC; ++d) dot += d1[d] * d2[d];
    float sq = a2[k] + a2[KPT + l] - 2.f * dot;
    sq = fmaxf(sq, 0.f);
    z = -sqrtf(sq + 1e-12f);
  }
  Z[t] = z;
}

// ---------------------------------------------------------------- sinkhorn halves
__device__ __forceinline__ float blk_reduce_max(float val, float* red) {
  #pragma unroll
  for (int off = 32; off; off >>= 1) val = fmaxf(val, __shfl_down(val, off));
  if ((threadIdx.x & 63) == 0) red[threadIdx.x >> 6] = val;
  __syncthreads();
  float r = fmaxf(fmaxf(red[0], red[1]), fmaxf(red[2], red[3]));
  __syncthreads();
  return r;
}

__device__ __forceinline__ float blk_reduce_sum(float val, float* red) {
  #pragma unroll
  for (int off = 32; off; off >>= 1) val += __shfl_down(val, off);
  if ((threadIdx.x & 63) == 0) red[threadIdx.x >> 6] = val;
  __syncthreads();
  float r = (red[0] + red[1]) + (red[2] + red[3]);
  __syncthreads();
  return r;
}

__global__ void sinkhorn_u_kernel(const float* __restrict__ Z, const float* __restrict__ v,
                                  float* __restrict__ u) {
  int k = blockIdx.x;           // 0..512
  __shared__ float red[4];
  const float* row = Z + (size_t)k * 513;
  int tid = threadIdx.x;
  float lm = -INFINITY;
  for (int l = tid; l < 513; l += 256) lm = fmaxf(lm, row[l] + v[l]);
  float m = blk_reduce_max(lm, red);
  float lsum = 0.f;
  for (int l = tid; l < 513; l += 256) lsum += expf(row[l] + v[l] - m);
  float s = blk_reduce_sum(lsum, red);
  if (tid == 0) {
    const float norm = -logf(1024.0f);
    float lmu = (k == KPT) ? (logf(512.0f) + norm) : norm;
    u[k] = lmu - (logf(s) + m);
  }
}

__global__ void sinkhorn_v_kernel(const float* __restrict__ Z, const float* __restrict__ u,
                                  float* __restrict__ v) {
  int l = blockIdx.x;           // 0..512
  __shared__ float red[4];
  int tid = threadIdx.x;
  float lm = -INFINITY;
  for (int kk = tid; kk < 513; kk += 256) lm = fmaxf(lm, Z[(size_t)kk * 513 + l] + u[kk]);
  float m = blk_reduce_max(lm, red);
  float lsum = 0.f;
  for (int kk = tid; kk < 513; kk += 256) lsum += expf(Z[(size_t)kk * 513 + l] + u[kk] - m);
  float s = blk_reduce_sum(lsum, red);
  if (tid == 0) {
    const float norm = -logf(1024.0f);
    float lnu = (l == KPT) ? (logf(512.0f) + norm) : norm;
    v[l] = lnu - (logf(s) + m);
  }
}

__global__ void probs_kernel(const float* __restrict__ Z, const float* __restrict__ u,
                             const float* __restrict__ v, float* __restrict__ out) {
  int t = blockIdx.x * blockDim.x + threadIdx.x;
  if (t >= 513 * 513) return;
  int k = t / 513;
  int l = t - k * 513;
  const float norm = -logf(1024.0f);
  float arg = Z[t] + u[k];
  arg += v[l];
  arg -= norm;
  out[t] = expf(arg);
}

// ---------------------------------------------------------------- launch
extern "C" void kernel_launch(void* const* d_in, const int* in_sizes, int n_in,
                              void* d_out, int out_size, void* d_ws, size_t ws_size,
                              hipStream_t stream) {
  const float* img1 = (const float*)d_in[0];
  const float* img2 = (const float*)d_in[1];
  float* out = (float*)d_out;

  char* p = (char*)d_ws;
  auto alloc = [&](size_t bytes) { char* r = p; p += (bytes + 255) & ~(size_t)255; return r; };
  int*   offs     = (int*)alloc(1024 * 4);
  int*   counts   = (int*)alloc(2 * 4);
  float* sel_val  = (float*)alloc(2 * KPT * 4);
  int*   sel_idx  = (int*)alloc(2 * KPT * 4);
  float* uu       = (float*)alloc(513 * 4);
  float* vv       = (float*)alloc(513 * 4);
  float* a2       = (float*)alloc(2 * KPT * 4);
  float* scores   = (float*)alloc((size_t)2 * HW * 4);
  float* smooth   = (float*)alloc((size_t)2 * HW * 4);
  float* cand_val = (float*)alloc((size_t)2 * CAP * 4);
  int*   cand_idx = (int*)alloc((size_t)2 * CAP * 4);
  float* desc     = (float*)alloc((size_t)2 * KPT * DESC * 4);
  float* Z        = (float*)alloc((size_t)513 * 513 * 4);

  init_offsets_kernel<<<1, 64, 0, stream>>>(offs);
  init_misc_kernel<<<8, 256, 0, stream>>>(counts, sel_val, sel_idx, uu, vv);
  detector_kernel<<<(2 * HW + 255) / 256, 256, 0, stream>>>(img1, img2, scores, smooth);
  nms_cand_kernel<<<(2 * HW + 255) / 256, 256, 0, stream>>>(scores, cand_val, cand_idx, counts);
  select_topk_kernel<<<dim3(CAP / 256, 2), 256, 0, stream>>>(cand_val, cand_idx, counts, sel_val, sel_idx);
  kp_desc_kernel<<<1024, 64, 0, stream>>>(sel_val, sel_idx, smooth, offs, desc, a2, out);
  similarity_kernel<<<(513 * 513 + 255) / 256, 256, 0, stream>>>(desc, a2, Z);
  for (int it = 0; it < 20; ++it) {
    sinkhorn_u_kernel<<<513, 256, 0, stream>>>(Z, vv, uu);
    sinkhorn_v_kernel<<<513, 256, 0, stream>>>(Z, uu, vv);
  }
  probs_kernel<<<(513 * 513 + 255) / 256, 256, 0, stream>>>(Z, uu, vv, out + 2048);
}

// Round 3
// 528.567 us; speedup vs baseline: 2.3708x; 1.5765x over previous
//
#include <hip/hip_runtime.h>
#include <math.h>

#define IMH 480
#define IMW 640
#define HW (IMH*IMW)
#define KPT 512
#define DESC 256
#define CAP 32768
#define NMSR 3

// ---------------------------------------------------------------- MT19937
// Replicates np.random.RandomState(42).uniform(-8,8,(256,4)) -> round -> int.
// Parallel twist: phases [0,227) / [227,454) / [454,623) / {623} — within each
// phase every element depends only on OLD state or on values produced by an
// earlier phase, so 256 threads + __syncthreads reproduce the serial order
// bit-exactly. Seed chain stays serial on thread 0 (registers, write-only LDS).
__global__ void init_offsets_kernel(int* __restrict__ offs) {
  __shared__ unsigned int mt[624];
  __shared__ unsigned int old[624];
  __shared__ unsigned int tp[2496];   // 4 generations x 624 tempered draws
  const int tid = threadIdx.x;
  if (tid == 0) {
    unsigned int s = 42u;
    for (int i = 0; i < 624; ++i) { mt[i] = s; s = 1812433253u * (s ^ (s >> 30)) + (unsigned)i + 1u; }
  }
  __syncthreads();
  for (int g = 0; g < 4; ++g) {
    for (int k = tid; k < 624; k += 256) old[k] = mt[k];
    __syncthreads();
    // phase 1: k in [0,227) — all inputs old
    for (int k = tid; k < 227; k += 256) {
      unsigned int y = (old[k] & 0x80000000u) | (old[k + 1] & 0x7fffffffu);
      mt[k] = old[k + 397] ^ (y >> 1) ^ ((y & 1u) ? 0x9908b0dfu : 0u);
    }
    __syncthreads();
    // phase 2a: k in [227,454) — reads new mt[k-227] from phase 1
    for (int k = 227 + tid; k < 454; k += 256) {
      unsigned int y = (old[k] & 0x80000000u) | (old[k + 1] & 0x7fffffffu);
      mt[k] = mt[k - 227] ^ (y >> 1) ^ ((y & 1u) ? 0x9908b0dfu : 0u);
    }
    __syncthreads();
    // phase 2b: k in [454,623) — reads new mt[k-227] from phase 2a
    for (int k = 454 + tid; k < 623; k += 256) {
      unsigned int y = (old[k] & 0x80000000u) | (old[k + 1] & 0x7fffffffu);
      mt[k] = mt[k - 227] ^ (y >> 1) ^ ((y & 1u) ? 0x9908b0dfu : 0u);
    }
    __syncthreads();
    // phase 3: k = 623 — reads new mt[0], new mt[396]
    if (tid == 0) {
      unsigned int y = (old[623] & 0x80000000u) | (mt[0] & 0x7fffffffu);
      mt[623] = mt[396] ^ (y >> 1) ^ ((y & 1u) ? 0x9908b0dfu : 0u);
    }
    __syncthreads();
    // temper this generation
    for (int k = tid; k < 624; k += 256) {
      unsigned int y = mt[k];
      y ^= (y >> 11);
      y ^= (y << 7)  & 0x9d2c5680u;
      y ^= (y << 15) & 0xefc60000u;
      y ^= (y >> 18);
      tp[g * 624 + k] = y;
    }
    __syncthreads();
  }
  // uniform(-8,8) -> np.round (rint = half-to-even) -> int
  for (int i = tid; i < 1024; i += 256) {
    unsigned int a = tp[2 * i] >> 5, b = tp[2 * i + 1] >> 6;
    double r = ((double)a * 67108864.0 + (double)b) / 9007199254740992.0;
    offs[i] = (int)rint(-8.0 + 16.0 * r);
  }
}

__global__ void init_misc_kernel(int* __restrict__ counts, float* __restrict__ sel_val,
                                 int* __restrict__ sel_idx, float* __restrict__ u,
                                 float* __restrict__ v) {
  int t = blockIdx.x * blockDim.x + threadIdx.x;
  if (t < 2) counts[t] = 0;
  if (t < 2 * KPT) { sel_val[t] = 0.f; sel_idx[t] = -1; }
  if (t < KPT + 1) { u[t] = 0.f; v[t] = 0.f; }
}

// ---------------------------------------------------------------- detector
__global__ void detector_kernel(const float* __restrict__ img0, const float* __restrict__ img1,
                                float* __restrict__ scores, float* __restrict__ smooth) {
  int t = blockIdx.x * blockDim.x + threadIdx.x;
  if (t >= 2 * HW) return;
  int b = t / HW;
  int p = t - b * HW;
  int y = p / IMW;
  int x = p - y * IMW;
  const float* __restrict__ img = b ? img1 : img0;
  float a[5][5];
  #pragma unroll
  for (int i = 0; i < 5; ++i) {
    int yy = y + i - 2;
    #pragma unroll
    for (int j = 0; j < 5; ++j) {
      int xx = x + j - 2;
      a[i][j] = (yy >= 0 && yy < IMH && xx >= 0 && xx < IMW) ? img[yy * IMW + xx] : 0.f;
    }
  }
  float sm = 0.f;
  #pragma unroll
  for (int i = 0; i < 5; ++i)
    #pragma unroll
    for (int j = 0; j < 5; ++j) sm += a[i][j];
  smooth[t] = sm * (1.f / 25.f);

  float sxx = 0.f, syy = 0.f, sxy = 0.f;
  #pragma unroll
  for (int cy = -1; cy <= 1; ++cy) {
    #pragma unroll
    for (int cx = -1; cx <= 1; ++cx) {
      int yy = y + cy, xx = x + cx;
      if (yy < 0 || yy >= IMH || xx < 0 || xx >= IMW) continue;  // zero-pad box conv
      int iu = cy + 2, iv = cx + 2;
      float ix = (a[iu - 1][iv + 1] - a[iu - 1][iv - 1])
               + 2.f * (a[iu][iv + 1] - a[iu][iv - 1])
               + (a[iu + 1][iv + 1] - a[iu + 1][iv - 1]);
      float iy = (a[iu + 1][iv - 1] + 2.f * a[iu + 1][iv] + a[iu + 1][iv + 1])
               - (a[iu - 1][iv - 1] + 2.f * a[iu - 1][iv] + a[iu - 1][iv + 1]);
      sxx += ix * ix; syy += iy * iy; sxy += ix * iy;
    }
  }
  sxx *= (1.f / 9.f); syy *= (1.f / 9.f); sxy *= (1.f / 9.f);
  float half_tr = 0.5f * (sxx + syy);
  float hd = 0.5f * (sxx - syy);
  scores[t] = half_tr - sqrtf(hd * hd + sxy * sxy + 1e-12f);
}

// ---------------------------------------------------------------- NMS + compact
__global__ void nms_cand_kernel(const float* __restrict__ scores,
                                float* __restrict__ cand_val, int* __restrict__ cand_idx,
                                int* __restrict__ counts) {
  int t = blockIdx.x * blockDim.x + threadIdx.x;
  if (t >= 2 * HW) return;
  int b = t / HW;
  int p = t - b * HW;
  int y = p / IMW;
  int x = p - y * IMW;
  const float* sc = scores + b * HW;
  float s = sc[p];
  if (s <= 0.f) return;   // s*mask must be > 0 anyway
  float m = -INFINITY;
  int y0 = max(y - NMSR, 0), y1 = min(y + NMSR, IMH - 1);
  int x0 = max(x - NMSR, 0), x1 = min(x + NMSR, IMW - 1);
  for (int yy = y0; yy <= y1; ++yy)
    for (int xx = x0; xx <= x1; ++xx)
      m = fmaxf(m, sc[yy * IMW + xx]);
  if (s >= m - 1e-7f) {
    int slot = atomicAdd(&counts[b], 1);
    if (slot < CAP) {
      cand_val[b * CAP + slot] = s;
      cand_idx[b * CAP + slot] = p;
    }
  }
}

// ---------------------------------------------------------------- exact top-512 (stable order)
__global__ void select_topk_kernel(const float* __restrict__ cand_val, const int* __restrict__ cand_idx,
                                   const int* __restrict__ counts,
                                   float* __restrict__ sel_val, int* __restrict__ sel_idx) {
  int b = blockIdx.y;
  int n = counts[b]; if (n > CAP) n = CAP;
  if ((int)(blockIdx.x * 256) >= n) return;   // block-uniform early exit
  int i = blockIdx.x * 256 + threadIdx.x;
  const float* cv = cand_val + b * CAP;
  const int* ci = cand_idx + b * CAP;
  bool active = (i < n);
  float vi = active ? cv[i] : 0.f;
  int ii = active ? ci[i] : 0x7fffffff;
  __shared__ float sv[256];
  __shared__ int si[256];
  int rank = 0;
  for (int base = 0; base < n; base += 256) {
    int j = base + (int)threadIdx.x;
    sv[threadIdx.x] = (j < n) ? cv[j] : -INFINITY;   // sentinel never outranks (vi > 0)
    si[threadIdx.x] = (j < n) ? ci[j] : 0x7fffffff;
    __syncthreads();
    #pragma unroll 8
    for (int t = 0; t < 256; ++t) {
      float vj = sv[t]; int ij = si[t];
      rank += ((vj > vi) || (vj == vi && ij < ii)) ? 1 : 0;
    }
    __syncthreads();
  }
  if (active && rank < KPT) {
    sel_val[b * KPT + rank] = vi;
    sel_idx[b * KPT + rank] = ii;
  }
}

// ---------------------------------------------------------------- kp out + BAD desc + L2 norm
__global__ void kp_desc_kernel(const float* __restrict__ sel_val, const int* __restrict__ sel_idx,
                               const float* __restrict__ smooth, const int* __restrict__ offs,
                               float* __restrict__ desc, float* __restrict__ a2_out,
                               float* __restrict__ out) {
  int blk = blockIdx.x;          // 0..1023
  int b = blk >> 9;
  int k = blk & 511;
  int lane = threadIdx.x;        // 0..63 (one wave)
  float val = sel_val[b * KPT + k];
  int idx = sel_idx[b * KPT + k];
  bool valid = (val > 0.f) && (idx >= 0);
  int y = 0, x = 0;
  if (valid) { y = idx / IMW; x = idx - y * IMW; }
  const float* sm = smooth + b * HW;
  float d[4];
  #pragma unroll
  for (int t2 = 0; t2 < 4; ++t2) {
    int pp = (lane << 2) + t2;
    int oy1 = offs[4 * pp + 0], ox1 = offs[4 * pp + 1];
    int oy2 = offs[4 * pp + 2], ox2 = offs[4 * pp + 3];
    int ya = min(max(y + oy1, 0), IMH - 1), xa = min(max(x + ox1, 0), IMW - 1);
    int yb = min(max(y + oy2, 0), IMH - 1), xb = min(max(x + ox2, 0), IMW - 1);
    float v2 = sm[ya * IMW + xa] - sm[yb * IMW + xb];
    d[t2] = valid ? v2 : 0.f;
  }
  float ss = d[0] * d[0] + d[1] * d[1] + d[2] * d[2] + d[3] * d[3];
  #pragma unroll
  for (int off = 32; off; off >>= 1) ss += __shfl_down(ss, off);
  ss = __shfl(ss, 0);
  float scale = 1.f / (sqrtf(ss) + 1e-8f);
  float* dd = desc + (size_t)(b * KPT + k) * DESC;
  #pragma unroll
  for (int t2 = 0; t2 < 4; ++t2) dd[(lane << 2) + t2] = d[t2] * scale;
  if (lane == 0) {
    a2_out[b * KPT + k] = ss * scale * scale;
    float* kp = out + b * (2 * KPT) + k * 2;
    kp[0] = valid ? (float)y : -1.f;
    kp[1] = valid ? (float)x : -1.f;
  }
}

// ---------------------------------------------------------------- Z = sim with dustbin
__global__ void similarity_kernel(const float* __restrict__ desc, const float* __restrict__ a2,
                                  float* __restrict__ Z) {
  int t = blockIdx.x * blockDim.x + threadIdx.x;
  if (t >= 513 * 513) return;
  int k = t / 513;
  int l = t - k * 513;
  float z;
  if (k == KPT || l == KPT) {
    z = 1.0f;   // UNUSED / EPSILON
  } else {
    const float* d1 = desc + (size_t)k * DESC;
    const float* d2 = desc + (size_t)(KPT + l) * DESC;
    float dot = 0.f;
    #pragma unroll 8
    for (int d = 0; d < DESC; ++d) dot += d1[d] * d2[d];
    float sq = a2[k] + a2[KPT + l] - 2.f * dot;
    sq = fmaxf(sq, 0.f);
    z = -sqrtf(sq + 1e-12f);
  }
  Z[t] = z;
}

// ---------------------------------------------------------------- sinkhorn halves
__device__ __forceinline__ float blk_reduce_max(float val, float* red) {
  #pragma unroll
  for (int off = 32; off; off >>= 1) val = fmaxf(val, __shfl_down(val, off));
  if ((threadIdx.x & 63) == 0) red[threadIdx.x >> 6] = val;
  __syncthreads();
  float r = fmaxf(fmaxf(red[0], red[1]), fmaxf(red[2], red[3]));
  __syncthreads();
  return r;
}

__device__ __forceinline__ float blk_reduce_sum(float val, float* red) {
  #pragma unroll
  for (int off = 32; off; off >>= 1) val += __shfl_down(val, off);
  if ((threadIdx.x & 63) == 0) red[threadIdx.x >> 6] = val;
  __syncthreads();
  float r = (red[0] + red[1]) + (red[2] + red[3]);
  __syncthreads();
  return r;
}

__global__ void sinkhorn_u_kernel(const float* __restrict__ Z, const float* __restrict__ v,
                                  float* __restrict__ u) {
  int k = blockIdx.x;           // 0..512
  __shared__ float red[4];
  const float* row = Z + (size_t)k * 513;
  int tid = threadIdx.x;
  float lm = -INFINITY;
  for (int l = tid; l < 513; l += 256) lm = fmaxf(lm, row[l] + v[l]);
  float m = blk_reduce_max(lm, red);
  float lsum = 0.f;
  for (int l = tid; l < 513; l += 256) lsum += expf(row[l] + v[l] - m);
  float s = blk_reduce_sum(lsum, red);
  if (tid == 0) {
    const float norm = -logf(1024.0f);
    float lmu = (k == KPT) ? (logf(512.0f) + norm) : norm;
    u[k] = lmu - (logf(s) + m);
  }
}

__global__ void sinkhorn_v_kernel(const float* __restrict__ Z, const float* __restrict__ u,
                                  float* __restrict__ v) {
  int l = blockIdx.x;           // 0..512
  __shared__ float red[4];
  int tid = threadIdx.x;
  float lm = -INFINITY;
  for (int kk = tid; kk < 513; kk += 256) lm = fmaxf(lm, Z[(size_t)kk * 513 + l] + u[kk]);
  float m = blk_reduce_max(lm, red);
  float lsum = 0.f;
  for (int kk = tid; kk < 513; kk += 256) lsum += expf(Z[(size_t)kk * 513 + l] + u[kk] - m);
  float s = blk_reduce_sum(lsum, red);
  if (tid == 0) {
    const float norm = -logf(1024.0f);
    float lnu = (l == KPT) ? (logf(512.0f) + norm) : norm;
    v[l] = lnu - (logf(s) + m);
  }
}

__global__ void probs_kernel(const float* __restrict__ Z, const float* __restrict__ u,
                             const float* __restrict__ v, float* __restrict__ out) {
  int t = blockIdx.x * blockDim.x + threadIdx.x;
  if (t >= 513 * 513) return;
  int k = t / 513;
  int l = t - k * 513;
  const float norm = -logf(1024.0f);
  float arg = Z[t] + u[k];
  arg += v[l];
  arg -= norm;
  out[t] = expf(arg);
}

// ---------------------------------------------------------------- launch
extern "C" void kernel_launch(void* const* d_in, const int* in_sizes, int n_in,
                              void* d_out, int out_size, void* d_ws, size_t ws_size,
                              hipStream_t stream) {
  const float* img1 = (const float*)d_in[0];
  const float* img2 = (const float*)d_in[1];
  float* out = (float*)d_out;

  char* p = (char*)d_ws;
  auto alloc = [&](size_t bytes) { char* r = p; p += (bytes + 255) & ~(size_t)255; return r; };
  int*   offs     = (int*)alloc(1024 * 4);
  int*   counts   = (int*)alloc(2 * 4);
  float* sel_val  = (float*)alloc(2 * KPT * 4);
  int*   sel_idx  = (int*)alloc(2 * KPT * 4);
  float* uu       = (float*)alloc(513 * 4);
  float* vv       = (float*)alloc(513 * 4);
  float* a2       = (float*)alloc(2 * KPT * 4);
  float* scores   = (float*)alloc((size_t)2 * HW * 4);
  float* smooth   = (float*)alloc((size_t)2 * HW * 4);
  float* cand_val = (float*)alloc((size_t)2 * CAP * 4);
  int*   cand_idx = (int*)alloc((size_t)2 * CAP * 4);
  float* desc     = (float*)alloc((size_t)2 * KPT * DESC * 4);
  float* Z        = (float*)alloc((size_t)513 * 513 * 4);

  init_offsets_kernel<<<1, 256, 0, stream>>>(offs);
  init_misc_kernel<<<8, 256, 0, stream>>>(counts, sel_val, sel_idx, uu, vv);
  detector_kernel<<<(2 * HW + 255) / 256, 256, 0, stream>>>(img1, img2, scores, smooth);
  nms_cand_kernel<<<(2 * HW + 255) / 256, 256, 0, stream>>>(scores, cand_val, cand_idx, counts);
  select_topk_kernel<<<dim3(CAP / 256, 2), 256, 0, stream>>>(cand_val, cand_idx, counts, sel_val, sel_idx);
  kp_desc_kernel<<<1024, 64, 0, stream>>>(sel_val, sel_idx, smooth, offs, desc, a2, out);
  similarity_kernel<<<(513 * 513 + 255) / 256, 256, 0, stream>>>(desc, a2, Z);
  for (int it = 0; it < 20; ++it) {
    sinkhorn_u_kernel<<<513, 256, 0, stream>>>(Z, vv, uu);
    sinkhorn_v_kernel<<<513, 256, 0, stream>>>(Z, uu, vv);
  }
  probs_kernel<<<(513 * 513 + 255) / 256, 256, 0, stream>>>(Z, uu, vv, out + 2048);
}

// Round 4
// 485.684 us; speedup vs baseline: 2.5801x; 1.0883x over previous
//
#include <hip/hip_runtime.h>
#include <math.h>

#define IMH 480
#define IMW 640
#define HW (IMH*IMW)
#define KPT 512
#define DESC 256
#define CAP 32768
#define NMSR 3

// ---------------------------------------------------------------- MT19937
// Replicates np.random.RandomState(42).uniform(-8,8,(256,4)) -> round -> int.
__global__ void init_offsets_kernel(int* __restrict__ offs) {
  __shared__ unsigned int mt[624];
  __shared__ unsigned int old[624];
  __shared__ unsigned int tp[2496];   // 4 generations x 624 tempered draws
  const int tid = threadIdx.x;
  if (tid == 0) {
    unsigned int s = 42u;
    for (int i = 0; i < 624; ++i) { mt[i] = s; s = 1812433253u * (s ^ (s >> 30)) + (unsigned)i + 1u; }
  }
  __syncthreads();
  for (int g = 0; g < 4; ++g) {
    for (int k = tid; k < 624; k += 256) old[k] = mt[k];
    __syncthreads();
    for (int k = tid; k < 227; k += 256) {
      unsigned int y = (old[k] & 0x80000000u) | (old[k + 1] & 0x7fffffffu);
      mt[k] = old[k + 397] ^ (y >> 1) ^ ((y & 1u) ? 0x9908b0dfu : 0u);
    }
    __syncthreads();
    for (int k = 227 + tid; k < 454; k += 256) {
      unsigned int y = (old[k] & 0x80000000u) | (old[k + 1] & 0x7fffffffu);
      mt[k] = mt[k - 227] ^ (y >> 1) ^ ((y & 1u) ? 0x9908b0dfu : 0u);
    }
    __syncthreads();
    for (int k = 454 + tid; k < 623; k += 256) {
      unsigned int y = (old[k] & 0x80000000u) | (old[k + 1] & 0x7fffffffu);
      mt[k] = mt[k - 227] ^ (y >> 1) ^ ((y & 1u) ? 0x9908b0dfu : 0u);
    }
    __syncthreads();
    if (tid == 0) {
      unsigned int y = (old[623] & 0x80000000u) | (mt[0] & 0x7fffffffu);
      mt[623] = mt[396] ^ (y >> 1) ^ ((y & 1u) ? 0x9908b0dfu : 0u);
    }
    __syncthreads();
    for (int k = tid; k < 624; k += 256) {
      unsigned int y = mt[k];
      y ^= (y >> 11);
      y ^= (y << 7)  & 0x9d2c5680u;
      y ^= (y << 15) & 0xefc60000u;
      y ^= (y >> 18);
      tp[g * 624 + k] = y;
    }
    __syncthreads();
  }
  for (int i = tid; i < 1024; i += 256) {
    unsigned int a = tp[2 * i] >> 5, b = tp[2 * i + 1] >> 6;
    double r = ((double)a * 67108864.0 + (double)b) / 9007199254740992.0;
    offs[i] = (int)rint(-8.0 + 16.0 * r);
  }
}

__global__ void init_misc_kernel(int* __restrict__ counts, float* __restrict__ sel_val,
                                 int* __restrict__ sel_idx, float* __restrict__ u,
                                 float* __restrict__ v) {
  int t = blockIdx.x * blockDim.x + threadIdx.x;
  if (t < 2) counts[t] = 0;
  if (t < 2 * KPT) { sel_val[t] = 0.f; sel_idx[t] = -1; }
  if (t < KPT + 1) { u[t] = 0.f; v[t] = 0.f; }
}

// ---------------------------------------------------------------- detector (LDS-tiled)
#define DTW 64
#define DTH 16
__global__ void detector_kernel(const float* __restrict__ img0, const float* __restrict__ img1,
                                float* __restrict__ scores, float* __restrict__ smooth) {
  const int b = blockIdx.z;
  const int x0 = blockIdx.x * DTW;
  const int y0 = blockIdx.y * DTH;
  const float* __restrict__ img = b ? img1 : img0;
  __shared__ float tile[(DTH + 4) * (DTW + 4)];   // 20x68, zero-filled OOB
  const int tid = threadIdx.x;
  for (int i = tid; i < (DTH + 4) * (DTW + 4); i += 256) {
    int ly = i / (DTW + 4), lx = i - ly * (DTW + 4);
    int gy = y0 + ly - 2, gx = x0 + lx - 2;
    tile[i] = (gy >= 0 && gy < IMH && gx >= 0 && gx < IMW) ? img[gy * IMW + gx] : 0.f;
  }
  __syncthreads();
  for (int i = tid; i < DTH * DTW; i += 256) {
    int ly = i / DTW, lx = i - ly * DTW;
    int y = y0 + ly, x = x0 + lx;   // always in range (640%64==0, 480%16==0)
    float a[5][5];
    #pragma unroll
    for (int ii = 0; ii < 5; ++ii)
      #pragma unroll
      for (int jj = 0; jj < 5; ++jj)
        a[ii][jj] = tile[(ly + ii) * (DTW + 4) + lx + jj];
    float sm = 0.f;
    #pragma unroll
    for (int ii = 0; ii < 5; ++ii)
      #pragma unroll
      for (int jj = 0; jj < 5; ++jj) sm += a[ii][jj];
    smooth[b * HW + y * IMW + x] = sm * (1.f / 25.f);

    float sxx = 0.f, syy = 0.f, sxy = 0.f;
    #pragma unroll
    for (int cy = -1; cy <= 1; ++cy) {
      #pragma unroll
      for (int cx = -1; cx <= 1; ++cx) {
        int yy = y + cy, xx = x + cx;
        if (yy < 0 || yy >= IMH || xx < 0 || xx >= IMW) continue;  // zero-pad box conv
        int iu = cy + 2, iv = cx + 2;
        float ix = (a[iu - 1][iv + 1] - a[iu - 1][iv - 1])
                 + 2.f * (a[iu][iv + 1] - a[iu][iv - 1])
                 + (a[iu + 1][iv + 1] - a[iu + 1][iv - 1]);
        float iy = (a[iu + 1][iv - 1] + 2.f * a[iu + 1][iv] + a[iu + 1][iv + 1])
                 - (a[iu - 1][iv - 1] + 2.f * a[iu - 1][iv] + a[iu - 1][iv + 1]);
        sxx += ix * ix; syy += iy * iy; sxy += ix * iy;
      }
    }
    sxx *= (1.f / 9.f); syy *= (1.f / 9.f); sxy *= (1.f / 9.f);
    float half_tr = 0.5f * (sxx + syy);
    float hd = 0.5f * (sxx - syy);
    scores[b * HW + y * IMW + x] = half_tr - sqrtf(hd * hd + sxy * sxy + 1e-12f);
  }
}

// ---------------------------------------------------------------- NMS (separable 7x7 max, LDS-tiled) + compact
#define NTW 64
#define NTH 32
__global__ void nms_cand_kernel(const float* __restrict__ scores,
                                float* __restrict__ cand_val, int* __restrict__ cand_idx,
                                int* __restrict__ counts) {
  const int b = blockIdx.z;
  const int x0 = blockIdx.x * NTW;
  const int y0 = blockIdx.y * NTH;
  const float* __restrict__ sc = scores + b * HW;
  __shared__ float sm[(NTH + 6) * (NTW + 6)];   // 38x70 staged scores (-inf OOB)
  __shared__ float hm[(NTH + 6) * NTW];         // 38x64 horizontal 7-max
  const int tid = threadIdx.x;
  for (int i = tid; i < (NTH + 6) * (NTW + 6); i += 256) {
    int ly = i / (NTW + 6), lx = i - ly * (NTW + 6);
    int gy = y0 + ly - 3, gx = x0 + lx - 3;
    sm[i] = (gy >= 0 && gy < IMH && gx >= 0 && gx < IMW) ? sc[gy * IMW + gx] : -INFINITY;
  }
  __syncthreads();
  for (int i = tid; i < (NTH + 6) * NTW; i += 256) {
    int ly = i / NTW, lx = i - ly * NTW;
    const float* r = sm + ly * (NTW + 6) + lx;
    float m = r[0];
    #pragma unroll
    for (int d = 1; d < 7; ++d) m = fmaxf(m, r[d]);
    hm[i] = m;
  }
  __syncthreads();
  for (int i = tid; i < NTH * NTW; i += 256) {
    int ly = i / NTW, lx = i - ly * NTW;
    float s = sm[(ly + 3) * (NTW + 6) + lx + 3];
    if (s <= 0.f) continue;
    float m = hm[ly * NTW + lx];
    #pragma unroll
    for (int d = 1; d < 7; ++d) m = fmaxf(m, hm[(ly + d) * NTW + lx]);
    if (s >= m - 1e-7f) {
      int gy = y0 + ly, gx = x0 + lx;
      int slot = atomicAdd(&counts[b], 1);
      if (slot < CAP) {
        cand_val[b * CAP + slot] = s;
        cand_idx[b * CAP + slot] = gy * IMW + gx;
      }
    }
  }
}

// ---------------------------------------------------------------- exact top-512 (stable order)
__global__ void select_topk_kernel(const float* __restrict__ cand_val, const int* __restrict__ cand_idx,
                                   const int* __restrict__ counts,
                                   float* __restrict__ sel_val, int* __restrict__ sel_idx) {
  int b = blockIdx.y;
  int n = counts[b]; if (n > CAP) n = CAP;
  if ((int)(blockIdx.x * 256) >= n) return;   // block-uniform early exit
  int i = blockIdx.x * 256 + threadIdx.x;
  const float* cv = cand_val + b * CAP;
  const int* ci = cand_idx + b * CAP;
  bool active = (i < n);
  float vi = active ? cv[i] : 0.f;
  int ii = active ? ci[i] : 0x7fffffff;
  __shared__ float sv[256];
  __shared__ int si[256];
  int rank = 0;
  for (int base = 0; base < n; base += 256) {
    int j = base + (int)threadIdx.x;
    sv[threadIdx.x] = (j < n) ? cv[j] : -INFINITY;
    si[threadIdx.x] = (j < n) ? ci[j] : 0x7fffffff;
    __syncthreads();
    #pragma unroll 8
    for (int t = 0; t < 256; ++t) {
      float vj = sv[t]; int ij = si[t];
      rank += ((vj > vi) || (vj == vi && ij < ii)) ? 1 : 0;
    }
    __syncthreads();
  }
  if (active && rank < KPT) {
    sel_val[b * KPT + rank] = vi;
    sel_idx[b * KPT + rank] = ii;
  }
}

// ---------------------------------------------------------------- kp out + BAD desc + L2 norm
__global__ void kp_desc_kernel(const float* __restrict__ sel_val, const int* __restrict__ sel_idx,
                               const float* __restrict__ smooth, const int* __restrict__ offs,
                               float* __restrict__ desc, float* __restrict__ a2_out,
                               float* __restrict__ out) {
  int blk = blockIdx.x;          // 0..1023
  int b = blk >> 9;
  int k = blk & 511;
  int lane = threadIdx.x;        // 0..63 (one wave)
  float val = sel_val[b * KPT + k];
  int idx = sel_idx[b * KPT + k];
  bool valid = (val > 0.f) && (idx >= 0);
  int y = 0, x = 0;
  if (valid) { y = idx / IMW; x = idx - y * IMW; }
  const float* sm = smooth + b * HW;
  float d[4];
  #pragma unroll
  for (int t2 = 0; t2 < 4; ++t2) {
    int pp = (lane << 2) + t2;
    int oy1 = offs[4 * pp + 0], ox1 = offs[4 * pp + 1];
    int oy2 = offs[4 * pp + 2], ox2 = offs[4 * pp + 3];
    int ya = min(max(y + oy1, 0), IMH - 1), xa = min(max(x + ox1, 0), IMW - 1);
    int yb = min(max(y + oy2, 0), IMH - 1), xb = min(max(x + ox2, 0), IMW - 1);
    float v2 = sm[ya * IMW + xa] - sm[yb * IMW + xb];
    d[t2] = valid ? v2 : 0.f;
  }
  float ss = d[0] * d[0] + d[1] * d[1] + d[2] * d[2] + d[3] * d[3];
  #pragma unroll
  for (int off = 32; off; off >>= 1) ss += __shfl_down(ss, off);
  ss = __shfl(ss, 0);
  float scale = 1.f / (sqrtf(ss) + 1e-8f);
  float* dd = desc + (size_t)(b * KPT + k) * DESC;
  #pragma unroll
  for (int t2 = 0; t2 < 4; ++t2) dd[(lane << 2) + t2] = d[t2] * scale;
  if (lane == 0) {
    a2_out[b * KPT + k] = ss * scale * scale;
    float* kp = out + b * (2 * KPT) + k * 2;
    kp[0] = valid ? (float)y : -1.f;
    kp[1] = valid ? (float)x : -1.f;
  }
}

// ---------------------------------------------------------------- Z = sim with dustbin
__global__ void similarity_kernel(const float* __restrict__ desc, const float* __restrict__ a2,
                                  float* __restrict__ Z) {
  int t = blockIdx.x * blockDim.x + threadIdx.x;
  if (t >= 513 * 513) return;
  int k = t / 513;
  int l = t - k * 513;
  float z;
  if (k == KPT || l == KPT) {
    z = 1.0f;   // UNUSED / EPSILON
  } else {
    const float* d1 = desc + (size_t)k * DESC;
    const float* d2 = desc + (size_t)(KPT + l) * DESC;
    float dot = 0.f;
    #pragma unroll 8
    for (int d = 0; d < DESC; ++d) dot += d1[d] * d2[d];
    float sq = a2[k] + a2[KPT + l] - 2.f * dot;
    sq = fmaxf(sq, 0.f);
    z = -sqrtf(sq + 1e-12f);
  }
  Z[t] = z;
}

// ---------------------------------------------------------------- sinkhorn halves
__device__ __forceinline__ float blk_reduce_max(float val, float* red) {
  #pragma unroll
  for (int off = 32; off; off >>= 1) val = fmaxf(val, __shfl_down(val, off));
  if ((threadIdx.x & 63) == 0) red[threadIdx.x >> 6] = val;
  __syncthreads();
  float r = fmaxf(fmaxf(red[0], red[1]), fmaxf(red[2], red[3]));
  __syncthreads();
  return r;
}

__device__ __forceinline__ float blk_reduce_sum(float val, float* red) {
  #pragma unroll
  for (int off = 32; off; off >>= 1) val += __shfl_down(val, off);
  if ((threadIdx.x & 63) == 0) red[threadIdx.x >> 6] = val;
  __syncthreads();
  float r = (red[0] + red[1]) + (red[2] + red[3]);
  __syncthreads();
  return r;
}

__global__ void sinkhorn_u_kernel(const float* __restrict__ Z, const float* __restrict__ v,
                                  float* __restrict__ u) {
  int k = blockIdx.x;           // 0..512
  __shared__ float red[4];
  const float* row = Z + (size_t)k * 513;
  int tid = threadIdx.x;
  float lm = -INFINITY;
  for (int l = tid; l < 513; l += 256) lm = fmaxf(lm, row[l] + v[l]);
  float m = blk_reduce_max(lm, red);
  float lsum = 0.f;
  for (int l = tid; l < 513; l += 256) lsum += expf(row[l] + v[l] - m);
  float s = blk_reduce_sum(lsum, red);
  if (tid == 0) {
    const float norm = -logf(1024.0f);
    float lmu = (k == KPT) ? (logf(512.0f) + norm) : norm;
    u[k] = lmu - (logf(s) + m);
  }
}

__global__ void sinkhorn_v_kernel(const float* __restrict__ Z, const float* __restrict__ u,
                                  float* __restrict__ v) {
  int l = blockIdx.x;           // 0..512
  __shared__ float red[4];
  int tid = threadIdx.x;
  float lm = -INFINITY;
  for (int kk = tid; kk < 513; kk += 256) lm = fmaxf(lm, Z[(size_t)kk * 513 + l] + u[kk]);
  float m = blk_reduce_max(lm, red);
  float lsum = 0.f;
  for (int kk = tid; kk < 513; kk += 256) lsum += expf(Z[(size_t)kk * 513 + l] + u[kk] - m);
  float s = blk_reduce_sum(lsum, red);
  if (tid == 0) {
    const float norm = -logf(1024.0f);
    float lnu = (l == KPT) ? (logf(512.0f) + norm) : norm;
    v[l] = lnu - (logf(s) + m);
  }
}

__global__ void probs_kernel(const float* __restrict__ Z, const float* __restrict__ u,
                             const float* __restrict__ v, float* __restrict__ out) {
  int t = blockIdx.x * blockDim.x + threadIdx.x;
  if (t >= 513 * 513) return;
  int k = t / 513;
  int l = t - k * 513;
  const float norm = -logf(1024.0f);
  float arg = Z[t] + u[k];
  arg += v[l];
  arg -= norm;
  out[t] = expf(arg);
}

// ---------------------------------------------------------------- launch
extern "C" void kernel_launch(void* const* d_in, const int* in_sizes, int n_in,
                              void* d_out, int out_size, void* d_ws, size_t ws_size,
                              hipStream_t stream) {
  const float* img1 = (const float*)d_in[0];
  const float* img2 = (const float*)d_in[1];
  float* out = (float*)d_out;

  char* p = (char*)d_ws;
  auto alloc = [&](size_t bytes) { char* r = p; p += (bytes + 255) & ~(size_t)255; return r; };
  int*   offs     = (int*)alloc(1024 * 4);
  int*   counts   = (int*)alloc(2 * 4);
  float* sel_val  = (float*)alloc(2 * KPT * 4);
  int*   sel_idx  = (int*)alloc(2 * KPT * 4);
  float* uu       = (float*)alloc(513 * 4);
  float* vv       = (float*)alloc(513 * 4);
  float* a2       = (float*)alloc(2 * KPT * 4);
  float* scores   = (float*)alloc((size_t)2 * HW * 4);
  float* smooth   = (float*)alloc((size_t)2 * HW * 4);
  float* cand_val = (float*)alloc((size_t)2 * CAP * 4);
  int*   cand_idx = (int*)alloc((size_t)2 * CAP * 4);
  float* desc     = (float*)alloc((size_t)2 * KPT * DESC * 4);
  float* Z        = (float*)alloc((size_t)513 * 513 * 4);

  init_offsets_kernel<<<1, 256, 0, stream>>>(offs);
  init_misc_kernel<<<8, 256, 0, stream>>>(counts, sel_val, sel_idx, uu, vv);
  detector_kernel<<<dim3(IMW / DTW, IMH / DTH, 2), 256, 0, stream>>>(img1, img2, scores, smooth);
  nms_cand_kernel<<<dim3(IMW / NTW, IMH / NTH, 2), 256, 0, stream>>>(scores, cand_val, cand_idx, counts);
  select_topk_kernel<<<dim3(CAP / 256, 2), 256, 0, stream>>>(cand_val, cand_idx, counts, sel_val, sel_idx);
  kp_desc_kernel<<<1024, 64, 0, stream>>>(sel_val, sel_idx, smooth, offs, desc, a2, out);
  similarity_kernel<<<(513 * 513 + 255) / 256, 256, 0, stream>>>(desc, a2, Z);
  for (int it = 0; it < 20; ++it) {
    sinkhorn_u_kernel<<<513, 256, 0, stream>>>(Z, vv, uu);
    sinkhorn_v_kernel<<<513, 256, 0, stream>>>(Z, uu, vv);
  }
  probs_kernel<<<(513 * 513 + 255) / 256, 256, 0, stream>>>(Z, uu, vv, out + 2048);
}